// Round 6
// baseline (546.662 us; speedup 1.0000x reference)
//
#include <hip/hip_runtime.h>
#include <hip/hip_bf16.h>

// ---------------------------------------------------------------------------
// DGL GAT (2-layer, heads=4, out=32) + WeightedSumAndMax readout.
// Round 5: agg kernels re-laid out for 2 edges in flight per wave with 8B
//          gathers per lane (2x MLP, half the loop iterations); layer-1
//          fc1+res1 computed by one dual-output GEMM (X staged once).
// ---------------------------------------------------------------------------

#define HEADS 4
#define OUTF 32
#define HF 128            // HEADS*OUTF
#define IN_FEATS 74
#define PRED_DIM 128
#define NEG_SLOPE 0.2f
#define NEG_INF_ENC 0x007fffffu   // enc_f(-inf)

typedef __hip_bfloat16 bf16;
typedef __hip_bfloat162 bf16x2;

__device__ __forceinline__ unsigned enc_f(float f) {
  unsigned u = __float_as_uint(f);
  return (u & 0x80000000u) ? ~u : (u | 0x80000000u);
}
__device__ __forceinline__ float dec_f(unsigned k) {
  return (k & 0x80000000u) ? __uint_as_float(k & 0x7fffffffu)
                           : __uint_as_float(~k);
}
__device__ __forceinline__ unsigned pack_bf16(float a, float b) {
  bf16x2 h = __float22bfloat162_rn(make_float2(a, b));
  return *(unsigned*)&h;
}
__device__ __forceinline__ float2 unpack_bf16(unsigned u) {
  bf16x2 h = *(bf16x2*)&u;
  return __bfloat1622float2(h);
}
__device__ __forceinline__ float lrelu(float v) {
  return (v >= 0.f) ? v : NEG_SLOPE * v;
}

// ========================= node GEMM (single) =============================
// out[n][j] = dot(X[n,:K], W[:K,j]). 64 nodes x 128 cols/block, 8x4 per thr.
template <int K, bool OUT_BF16>
__global__ __launch_bounds__(256) void gemm_tiled(
    const float* __restrict__ X, const float* __restrict__ W,
    void* __restrict__ out_v, int N) {
  constexpr int BK = 32;
  constexpr int APAD = 68;
  __shared__ float as[BK * APAD];
  __shared__ float bs[BK * HF];
  const int tid = threadIdx.x;
  const int tx = tid & 31;
  const int ty = tid >> 5;
  const int j4 = tx * 4;
  const int nb = ty * 8;
  const int n0 = blockIdx.x * 64;

  float acc[8][4] = {};
  for (int k0 = 0; k0 < K; k0 += BK) {
#pragma unroll
    for (int i = 0; i < 8; ++i) {
      int idx = i * 256 + tid;
      int kk = idx & 31, nl = idx >> 5;
      int n = n0 + nl, k = k0 + kk;
      float v = 0.f;
      if (n < N && k < K) v = X[(size_t)n * K + k];
      as[kk * APAD + nl] = v;
    }
#pragma unroll
    for (int i = 0; i < 16; ++i) {
      int idx = i * 256 + tid;
      int kk = idx >> 7, c = idx & 127;
      int k = k0 + kk;
      bs[idx] = (k < K) ? W[(size_t)k * HF + c] : 0.f;
    }
    __syncthreads();
#pragma unroll 8
    for (int kk = 0; kk < BK; ++kk) {
      float4 wv = *(const float4*)&bs[kk * HF + j4];
      float4 a0 = *(const float4*)&as[kk * APAD + nb];
      float4 a1 = *(const float4*)&as[kk * APAD + nb + 4];
      float av[8] = {a0.x, a0.y, a0.z, a0.w, a1.x, a1.y, a1.z, a1.w};
#pragma unroll
      for (int i = 0; i < 8; ++i) {
        acc[i][0] = fmaf(av[i], wv.x, acc[i][0]);
        acc[i][1] = fmaf(av[i], wv.y, acc[i][1]);
        acc[i][2] = fmaf(av[i], wv.z, acc[i][2]);
        acc[i][3] = fmaf(av[i], wv.w, acc[i][3]);
      }
    }
    __syncthreads();
  }
#pragma unroll
  for (int i = 0; i < 8; ++i) {
    int n = n0 + nb + i;
    if (n >= N) continue;
    if (OUT_BF16) {
      bf16* out = (bf16*)out_v;
      *(uint2*)&out[(size_t)n * HF + j4] =
          make_uint2(pack_bf16(acc[i][0], acc[i][1]),
                     pack_bf16(acc[i][2], acc[i][3]));
    } else {
      float* out = (float*)out_v;
      *(float4*)&out[(size_t)n * HF + j4] =
          make_float4(acc[i][0], acc[i][1], acc[i][2], acc[i][3]);
    }
  }
}

// ========================= node GEMM (dual) ================================
// Two weight matrices over the same X (fc1 -> bf16 outA, res1 -> f32 outB).
// X staged once per tile; saves a full re-read of X and a dispatch.
template <int K>
__global__ __launch_bounds__(256) void gemm_dual(
    const float* __restrict__ X, const float* __restrict__ W1,
    const float* __restrict__ W2, bf16* __restrict__ outA,
    float* __restrict__ outB, int N) {
  constexpr int BK = 32;
  constexpr int APAD = 68;
  __shared__ float as[BK * APAD];
  __shared__ float bs1[BK * HF];
  __shared__ float bs2[BK * HF];
  const int tid = threadIdx.x;
  const int tx = tid & 31;
  const int ty = tid >> 5;
  const int j4 = tx * 4;
  const int nb = ty * 8;
  const int n0 = blockIdx.x * 64;

  float acc1[8][4] = {};
  float acc2[8][4] = {};
  for (int k0 = 0; k0 < K; k0 += BK) {
#pragma unroll
    for (int i = 0; i < 8; ++i) {
      int idx = i * 256 + tid;
      int kk = idx & 31, nl = idx >> 5;
      int n = n0 + nl, k = k0 + kk;
      float v = 0.f;
      if (n < N && k < K) v = X[(size_t)n * K + k];
      as[kk * APAD + nl] = v;
    }
#pragma unroll
    for (int i = 0; i < 16; ++i) {
      int idx = i * 256 + tid;
      int kk = idx >> 7, c = idx & 127;
      int k = k0 + kk;
      bs1[idx] = (k < K) ? W1[(size_t)k * HF + c] : 0.f;
      bs2[idx] = (k < K) ? W2[(size_t)k * HF + c] : 0.f;
    }
    __syncthreads();
#pragma unroll 4
    for (int kk = 0; kk < BK; ++kk) {
      float4 w1 = *(const float4*)&bs1[kk * HF + j4];
      float4 w2 = *(const float4*)&bs2[kk * HF + j4];
      float4 a0 = *(const float4*)&as[kk * APAD + nb];
      float4 a1 = *(const float4*)&as[kk * APAD + nb + 4];
      float av[8] = {a0.x, a0.y, a0.z, a0.w, a1.x, a1.y, a1.z, a1.w};
#pragma unroll
      for (int i = 0; i < 8; ++i) {
        acc1[i][0] = fmaf(av[i], w1.x, acc1[i][0]);
        acc1[i][1] = fmaf(av[i], w1.y, acc1[i][1]);
        acc1[i][2] = fmaf(av[i], w1.z, acc1[i][2]);
        acc1[i][3] = fmaf(av[i], w1.w, acc1[i][3]);
        acc2[i][0] = fmaf(av[i], w2.x, acc2[i][0]);
        acc2[i][1] = fmaf(av[i], w2.y, acc2[i][1]);
        acc2[i][2] = fmaf(av[i], w2.z, acc2[i][2]);
        acc2[i][3] = fmaf(av[i], w2.w, acc2[i][3]);
      }
    }
    __syncthreads();
  }
#pragma unroll
  for (int i = 0; i < 8; ++i) {
    int n = n0 + nb + i;
    if (n >= N) continue;
    *(uint2*)&outA[(size_t)n * HF + j4] =
        make_uint2(pack_bf16(acc1[i][0], acc1[i][1]),
                   pack_bf16(acc1[i][2], acc1[i][3]));
    *(float4*)&outB[(size_t)n * HF + j4] =
        make_float4(acc2[i][0], acc2[i][1], acc2[i][2], acc2[i][3]);
  }
}

// ============================ CSR build ====================================
__global__ __launch_bounds__(256) void hist_kernel(
    const int* __restrict__ dst, int* __restrict__ deg, int E) {
  int e = blockIdx.x * 256 + threadIdx.x;
  if (e < E) atomicAdd(&deg[dst[e]], 1);
}

__global__ __launch_bounds__(256) void scan1_kernel(
    const int* __restrict__ deg, int* __restrict__ row_ptr,
    int* __restrict__ bsum, int N) {
  const int base = blockIdx.x * 2048;
  const int tbase = base + threadIdx.x * 8;
  int vals[8];
  int tsum = 0;
#pragma unroll
  for (int i = 0; i < 8; ++i) {
    int idx = tbase + i;
    vals[i] = (idx < N) ? deg[idx] : 0;
    tsum += vals[i];
  }
  const int lane = threadIdx.x & 63, wv = threadIdx.x >> 6;
  int incl = tsum;
#pragma unroll
  for (int off = 1; off < 64; off <<= 1) {
    int nv = __shfl_up(incl, off);
    if (lane >= off) incl += nv;
  }
  __shared__ int wsum[4];
  if (lane == 63) wsum[wv] = incl;
  __syncthreads();
  int woff = 0;
  for (int w = 0; w < wv; ++w) woff += wsum[w];
  int run = woff + incl - tsum;
#pragma unroll
  for (int i = 0; i < 8; ++i) {
    int idx = tbase + i;
    if (idx < N) row_ptr[idx] = run;
    run += vals[i];
  }
  if (threadIdx.x == 255) bsum[blockIdx.x] = woff + incl;
}

__global__ __launch_bounds__(64) void scan2_kernel(
    const int* __restrict__ bsum, int* __restrict__ bpre, int NB) {
  const int lane = threadIdx.x;
  int running = 0;
  for (int c = 0; c < NB; c += 64) {
    int v = (c + lane < NB) ? bsum[c + lane] : 0;
    int incl = v;
#pragma unroll
    for (int off = 1; off < 64; off <<= 1) {
      int nv = __shfl_up(incl, off);
      if (lane >= off) incl += nv;
    }
    if (c + lane < NB) bpre[c + lane] = running + incl - v;
    running += __shfl(incl, 63);
  }
}

__global__ __launch_bounds__(256) void scan3_kernel(
    int* __restrict__ row_ptr, const int* __restrict__ bpre, int N, int E) {
  int t = blockIdx.x * 256 + threadIdx.x;
  if (t < N) row_ptr[t] += bpre[t >> 11];
  if (t == 0) row_ptr[N] = E;
}

__global__ __launch_bounds__(256) void scatter_kernel(
    const int* __restrict__ src, const int* __restrict__ dst,
    const int* __restrict__ row_ptr, int* __restrict__ cursor,
    int* __restrict__ ssorted, int E) {
  int e = blockIdx.x * 256 + threadIdx.x;
  if (e >= E) return;
  int d = dst[e];
  int pos = row_ptr[d] + atomicAdd(&cursor[d], 1);
  ssorted[pos] = src[e];
}

// ===================== attention scores ==========================
__global__ __launch_bounds__(256) void scores_kernel(
    const bf16* __restrict__ feat, const float* __restrict__ attn_l,
    const float* __restrict__ attn_r, float* __restrict__ el,
    float* __restrict__ er, int N) {
  int t = blockIdx.x * 256 + threadIdx.x;
  if (t >= N * HEADS) return;
  int h = t & 3;
  const bf16x2* f2 = (const bf16x2*)(feat + (size_t)t * OUTF);
  const float* al = attn_l + h * OUTF;
  const float* ar = attn_r + h * OUTF;
  float sl = 0.f, sr = 0.f;
#pragma unroll
  for (int k = 0; k < OUTF / 2; ++k) {
    float2 v = __bfloat1622float2(f2[k]);
    sl = fmaf(v.x, al[2 * k], sl);
    sl = fmaf(v.y, al[2 * k + 1], sl);
    sr = fmaf(v.x, ar[2 * k], sr);
    sr = fmaf(v.y, ar[2 * k + 1], sr);
  }
  el[t] = sl;
  er[t] = sr;
}

// ============ fused softmax + aggregate (single edge pass) =================
// One wave per node. lane = g*32 + c: g = edge group (2 edges in flight),
// c = col group (cols c*4..c*4+3, 8B bf16 gather per lane), head h = c>>3.
// alpha = exp(v)/sum(exp) without max-subtraction (v bounded).
// Layer 1 epilogue: B[n] = elu(inv*agg + B[n] + bias)   (in place)
__global__ __launch_bounds__(256) void agg1_fused(
    const int* __restrict__ row_ptr, const int* __restrict__ ssorted,
    const float* __restrict__ el, const float* __restrict__ er,
    const bf16* __restrict__ feat, float* __restrict__ B,
    const float* __restrict__ bias, int N) {
  int n = blockIdx.x * 4 + (threadIdx.x >> 6);
  if (n >= N) return;
  const int lane = threadIdx.x & 63;
  const int g = lane >> 5;
  const int c = lane & 31;
  const int h = c >> 3;
  const int rb = row_ptr[n], re = row_ptr[n + 1];
  const float ern = er[n * HEADS + h];

  float a0 = 0.f, a1 = 0.f, a2 = 0.f, a3 = 0.f, ssum = 0.f;
  for (int base = rb; base < re; base += 2) {
    int e = base + g;
    if (e < re) {
      int s = ssorted[e];
      float x = __expf(lrelu(el[s * HEADS + h] + ern));
      uint2 fr = *(const uint2*)&feat[(size_t)s * HF + c * 4];
      float2 p0 = unpack_bf16(fr.x), p1 = unpack_bf16(fr.y);
      ssum += x;
      a0 = fmaf(x, p0.x, a0); a1 = fmaf(x, p0.y, a1);
      a2 = fmaf(x, p1.x, a2); a3 = fmaf(x, p1.y, a3);
    }
  }
  a0 += __shfl_xor(a0, 32); a1 += __shfl_xor(a1, 32);
  a2 += __shfl_xor(a2, 32); a3 += __shfl_xor(a3, 32);
  ssum += __shfl_xor(ssum, 32);
  if (lane < 32) {
    float inv = 1.f / ssum;
    float4 r = *(const float4*)&B[(size_t)n * HF + c * 4];
    float4 bi = *(const float4*)&bias[c * 4];
    float v0 = fmaf(a0, inv, r.x + bi.x);
    float v1 = fmaf(a1, inv, r.y + bi.y);
    float v2 = fmaf(a2, inv, r.z + bi.z);
    float v3 = fmaf(a3, inv, r.w + bi.w);
    v0 = (v0 > 0.f) ? v0 : expm1f(v0);
    v1 = (v1 > 0.f) ? v1 : expm1f(v1);
    v2 = (v2 > 0.f) ? v2 : expm1f(v2);
    v3 = (v3 > 0.f) ? v3 : expm1f(v3);
    *(float4*)&B[(size_t)n * HF + c * 4] = make_float4(v0, v1, v2, v3);
  }
}

// Layer 2 epilogue: head-mean -> sigmoid gate -> readout atomics.
__global__ __launch_bounds__(256) void agg2_fused(
    const int* __restrict__ row_ptr, const int* __restrict__ ssorted,
    const float* __restrict__ el, const float* __restrict__ er,
    const bf16* __restrict__ feat, const float* __restrict__ h1,
    const float* __restrict__ bias, const float* __restrict__ ww,
    const float* __restrict__ wb, const int* __restrict__ gids,
    float* __restrict__ hsum, unsigned* __restrict__ hmax, int N) {
  int n = blockIdx.x * 4 + (threadIdx.x >> 6);
  if (n >= N) return;
  const int lane = threadIdx.x & 63;
  const int g = lane >> 5;
  const int c = lane & 31;
  const int h = c >> 3;
  const int rb = row_ptr[n], re = row_ptr[n + 1];
  const float ern = er[n * HEADS + h];

  float a0 = 0.f, a1 = 0.f, a2 = 0.f, a3 = 0.f, ssum = 0.f;
  for (int base = rb; base < re; base += 2) {
    int e = base + g;
    if (e < re) {
      int s = ssorted[e];
      float x = __expf(lrelu(el[s * HEADS + h] + ern));
      uint2 fr = *(const uint2*)&feat[(size_t)s * HF + c * 4];
      float2 p0 = unpack_bf16(fr.x), p1 = unpack_bf16(fr.y);
      ssum += x;
      a0 = fmaf(x, p0.x, a0); a1 = fmaf(x, p0.y, a1);
      a2 = fmaf(x, p1.x, a2); a3 = fmaf(x, p1.y, a3);
    }
  }
  a0 += __shfl_xor(a0, 32); a1 += __shfl_xor(a1, 32);
  a2 += __shfl_xor(a2, 32); a3 += __shfl_xor(a3, 32);
  ssum += __shfl_xor(ssum, 32);
  if (lane < 32) {
    float inv = 1.f / ssum;
    float4 r = *(const float4*)&h1[(size_t)n * HF + c * 4];
    float4 bi = *(const float4*)&bias[c * 4];
    a0 = fmaf(a0, inv, r.x + bi.x);
    a1 = fmaf(a1, inv, r.y + bi.y);
    a2 = fmaf(a2, inv, r.z + bi.z);
    a3 = fmaf(a3, inv, r.w + bi.w);
    // head mean: lanes c, c^8, c^16, c^24 hold the 4 heads of the same f cols
#pragma unroll
    for (int off = 8; off < 32; off <<= 1) {
      a0 += __shfl_xor(a0, off);
      a1 += __shfl_xor(a1, off);
      a2 += __shfl_xor(a2, off);
      a3 += __shfl_xor(a3, off);
    }
    a0 *= 0.25f; a1 *= 0.25f; a2 *= 0.25f; a3 *= 0.25f;
    // sigmoid gate: dot(node_feats, ww), reduced over the 8 col groups
    int f = (c & 7) * 4;
    float d = a0 * ww[f] + a1 * ww[f + 1] + a2 * ww[f + 2] + a3 * ww[f + 3];
#pragma unroll
    for (int off = 1; off < 8; off <<= 1) d += __shfl_xor(d, off);
    float wv = 1.f / (1.f + __expf(-(d + wb[0])));
    if (lane < 8) {
      int gi = gids[n];
      atomicAdd(&hsum[gi * OUTF + f], wv * a0);
      atomicAdd(&hsum[gi * OUTF + f + 1], wv * a1);
      atomicAdd(&hsum[gi * OUTF + f + 2], wv * a2);
      atomicAdd(&hsum[gi * OUTF + f + 3], wv * a3);
      atomicMax(&hmax[gi * OUTF + f], enc_f(a0));
      atomicMax(&hmax[gi * OUTF + f + 1], enc_f(a1));
      atomicMax(&hmax[gi * OUTF + f + 2], enc_f(a2));
      atomicMax(&hmax[gi * OUTF + f + 3], enc_f(a3));
    }
  }
}

// ============================ readout tail =================================
__global__ __launch_bounds__(256) void init_readout_kernel(
    float* __restrict__ hsum, unsigned* __restrict__ hmax, int g32) {
  int t = blockIdx.x * 256 + threadIdx.x;
  if (t >= g32) return;
  hsum[t] = 0.f;
  hmax[t] = NEG_INF_ENC;
}

__global__ __launch_bounds__(256) void final_gemm_kernel(
    const float* __restrict__ hsum, const unsigned* __restrict__ hmax,
    const float* __restrict__ tw, const float* __restrict__ tb,
    float* __restrict__ out, int G) {
  __shared__ float tws[64 * PRED_DIM];
  for (int i = threadIdx.x; i < 64 * PRED_DIM; i += 256) tws[i] = tw[i];
  __syncthreads();
  int g = blockIdx.x * 2 + (threadIdx.x >> 7);
  int p = threadIdx.x & 127;
  if (g >= G) return;
  float acc = tb[p];
#pragma unroll
  for (int k = 0; k < OUTF; ++k)
    acc = fmaf(hsum[g * OUTF + k], tws[k * PRED_DIM + p], acc);
#pragma unroll
  for (int k = 0; k < OUTF; ++k)
    acc = fmaf(dec_f(hmax[g * OUTF + k]), tws[(OUTF + k) * PRED_DIM + p], acc);
  out[(size_t)g * PRED_DIM + p] = acc;
}

static inline int cdiv(long long a, int b) { return (int)((a + b - 1) / b); }

extern "C" void kernel_launch(void* const* d_in, const int* in_sizes, int n_in,
                              void* d_out, int out_size, void* d_ws,
                              size_t ws_size, hipStream_t stream) {
  const float* feats   = (const float*)d_in[0];
  const int*   src     = (const int*)d_in[1];
  const int*   dst     = (const int*)d_in[2];
  const int*   gids    = (const int*)d_in[3];
  const float* fc1_w   = (const float*)d_in[4];
  const float* attn_l1 = (const float*)d_in[5];
  const float* attn_r1 = (const float*)d_in[6];
  const float* res1_w  = (const float*)d_in[7];
  const float* bias1   = (const float*)d_in[8];
  const float* fc2_w   = (const float*)d_in[9];
  const float* attn_l2 = (const float*)d_in[10];
  const float* attn_r2 = (const float*)d_in[11];
  const float* bias2   = (const float*)d_in[12];
  const float* ww      = (const float*)d_in[13];
  const float* wb      = (const float*)d_in[14];
  const float* tw      = (const float*)d_in[15];
  const float* tb      = (const float*)d_in[16];
  float* out = (float*)d_out;

  const int N = in_sizes[0] / IN_FEATS;  // 100000
  const int E = in_sizes[1];             // 900000
  const int G = out_size / PRED_DIM;     // 2048
  const int NB = cdiv(N, 2048);

  // ---- workspace layout ----
  bf16* A = (bf16*)d_ws;                                   // N*128 bf16
  float* B  = (float*)((char*)d_ws + (size_t)N * HF * 2);  // N*128 f32
  float* el = B + (size_t)N * HF;        // N*4
  float* er = el + (size_t)N * HEADS;    // N*4
  float* hsum = er + (size_t)N * HEADS;  // G*32
  unsigned* hmax = (unsigned*)(hsum + (size_t)G * OUTF);   // G*32
  int* deg     = (int*)(hmax + (size_t)G * OUTF);  // N
  int* cursor  = deg + N;                          // N
  int* row_ptr = cursor + N;                       // N+1
  int* ssorted = row_ptr + (N + 1);                // E
  int* bsum    = ssorted + E;                      // NB
  int* bpre    = bsum + NB;                        // NB

  const int n4 = N * HEADS;
  const int gblk = cdiv(N, 64);
  const int nwblk = cdiv(N, 4);

  // ===================== CSR build =====================
  hipMemsetAsync(deg, 0, (size_t)N * sizeof(int), stream);
  hipMemsetAsync(cursor, 0, (size_t)N * sizeof(int), stream);
  hist_kernel<<<cdiv(E, 256), 256, 0, stream>>>(dst, deg, E);
  scan1_kernel<<<NB, 256, 0, stream>>>(deg, row_ptr, bsum, N);
  scan2_kernel<<<1, 64, 0, stream>>>(bsum, bpre, NB);
  scan3_kernel<<<cdiv(N, 256), 256, 0, stream>>>(row_ptr, bpre, N, E);
  scatter_kernel<<<cdiv(E, 256), 256, 0, stream>>>(src, dst, row_ptr, cursor,
                                                   ssorted, E);

  // ===================== Layer 1 =====================
  gemm_dual<IN_FEATS><<<gblk, 256, 0, stream>>>(feats, fc1_w, res1_w, A, B, N);
  scores_kernel<<<cdiv(n4, 256), 256, 0, stream>>>(A, attn_l1, attn_r1, el, er, N);
  agg1_fused<<<nwblk, 256, 0, stream>>>(row_ptr, ssorted, el, er, A, B, bias1, N);

  // ===================== Layer 2 =====================
  gemm_tiled<HF, true><<<gblk, 256, 0, stream>>>(B, fc2_w, A, N);
  scores_kernel<<<cdiv(n4, 256), 256, 0, stream>>>(A, attn_l2, attn_r2, el, er, N);
  init_readout_kernel<<<cdiv(G * OUTF, 256), 256, 0, stream>>>(hsum, hmax,
                                                               G * OUTF);
  agg2_fused<<<nwblk, 256, 0, stream>>>(row_ptr, ssorted, el, er, A, B, bias2,
                                        ww, wb, gids, hsum, hmax, N);

  // ===================== Readout =====================
  final_gemm_kernel<<<cdiv(G, 2), 256, 0, stream>>>(hsum, hmax, tw, tb, out, G);
}

// Round 7
// 512.082 us; speedup vs baseline: 1.0675x; 1.0675x over previous
//
#include <hip/hip_runtime.h>
#include <hip/hip_bf16.h>

// ---------------------------------------------------------------------------
// DGL GAT (2-layer, heads=4, out=32) + WeightedSumAndMax readout.
// Round 6: revert round-5 regressions (gemm_dual, predicated agg loop);
//          agg kernels use round-4 lane layout with 4-edge straight-line
//          unroll (12 independent gathers in flight per wave).
// ---------------------------------------------------------------------------

#define HEADS 4
#define OUTF 32
#define HF 128            // HEADS*OUTF
#define IN_FEATS 74
#define PRED_DIM 128
#define NEG_SLOPE 0.2f
#define NEG_INF_ENC 0x007fffffu   // enc_f(-inf)

typedef __hip_bfloat16 bf16;
typedef __hip_bfloat162 bf16x2;

__device__ __forceinline__ unsigned enc_f(float f) {
  unsigned u = __float_as_uint(f);
  return (u & 0x80000000u) ? ~u : (u | 0x80000000u);
}
__device__ __forceinline__ float dec_f(unsigned k) {
  return (k & 0x80000000u) ? __uint_as_float(k & 0x7fffffffu)
                           : __uint_as_float(~k);
}
__device__ __forceinline__ unsigned pack_bf16(float a, float b) {
  bf16x2 h = __float22bfloat162_rn(make_float2(a, b));
  return *(unsigned*)&h;
}
__device__ __forceinline__ float2 unpack_bf16(unsigned u) {
  bf16x2 h = *(bf16x2*)&u;
  return __bfloat1622float2(h);
}
__device__ __forceinline__ float lrelu(float v) {
  return (v >= 0.f) ? v : NEG_SLOPE * v;
}

// ========================= node GEMM =============================
// out[n][j] = dot(X[n,:K], W[:K,j]). 64 nodes x 128 cols/block, 8x4 per thr.
template <int K, bool OUT_BF16>
__global__ __launch_bounds__(256) void gemm_tiled(
    const float* __restrict__ X, const float* __restrict__ W,
    void* __restrict__ out_v, int N) {
  constexpr int BK = 32;
  constexpr int APAD = 68;
  __shared__ float as[BK * APAD];
  __shared__ float bs[BK * HF];
  const int tid = threadIdx.x;
  const int tx = tid & 31;
  const int ty = tid >> 5;
  const int j4 = tx * 4;
  const int nb = ty * 8;
  const int n0 = blockIdx.x * 64;

  float acc[8][4] = {};
  for (int k0 = 0; k0 < K; k0 += BK) {
#pragma unroll
    for (int i = 0; i < 8; ++i) {
      int idx = i * 256 + tid;
      int kk = idx & 31, nl = idx >> 5;
      int n = n0 + nl, k = k0 + kk;
      float v = 0.f;
      if (n < N && k < K) v = X[(size_t)n * K + k];
      as[kk * APAD + nl] = v;
    }
#pragma unroll
    for (int i = 0; i < 16; ++i) {
      int idx = i * 256 + tid;
      int kk = idx >> 7, c = idx & 127;
      int k = k0 + kk;
      bs[idx] = (k < K) ? W[(size_t)k * HF + c] : 0.f;
    }
    __syncthreads();
#pragma unroll 8
    for (int kk = 0; kk < BK; ++kk) {
      float4 wv = *(const float4*)&bs[kk * HF + j4];
      float4 a0 = *(const float4*)&as[kk * APAD + nb];
      float4 a1 = *(const float4*)&as[kk * APAD + nb + 4];
      float av[8] = {a0.x, a0.y, a0.z, a0.w, a1.x, a1.y, a1.z, a1.w};
#pragma unroll
      for (int i = 0; i < 8; ++i) {
        acc[i][0] = fmaf(av[i], wv.x, acc[i][0]);
        acc[i][1] = fmaf(av[i], wv.y, acc[i][1]);
        acc[i][2] = fmaf(av[i], wv.z, acc[i][2]);
        acc[i][3] = fmaf(av[i], wv.w, acc[i][3]);
      }
    }
    __syncthreads();
  }
#pragma unroll
  for (int i = 0; i < 8; ++i) {
    int n = n0 + nb + i;
    if (n >= N) continue;
    if (OUT_BF16) {
      bf16* out = (bf16*)out_v;
      *(uint2*)&out[(size_t)n * HF + j4] =
          make_uint2(pack_bf16(acc[i][0], acc[i][1]),
                     pack_bf16(acc[i][2], acc[i][3]));
    } else {
      float* out = (float*)out_v;
      *(float4*)&out[(size_t)n * HF + j4] =
          make_float4(acc[i][0], acc[i][1], acc[i][2], acc[i][3]);
    }
  }
}

// ============================ CSR build ====================================
__global__ __launch_bounds__(256) void hist_kernel(
    const int* __restrict__ dst, int* __restrict__ deg, int E) {
  int e = blockIdx.x * 256 + threadIdx.x;
  if (e < E) atomicAdd(&deg[dst[e]], 1);
}

__global__ __launch_bounds__(256) void scan1_kernel(
    const int* __restrict__ deg, int* __restrict__ row_ptr,
    int* __restrict__ bsum, int N) {
  const int base = blockIdx.x * 2048;
  const int tbase = base + threadIdx.x * 8;
  int vals[8];
  int tsum = 0;
#pragma unroll
  for (int i = 0; i < 8; ++i) {
    int idx = tbase + i;
    vals[i] = (idx < N) ? deg[idx] : 0;
    tsum += vals[i];
  }
  const int lane = threadIdx.x & 63, wv = threadIdx.x >> 6;
  int incl = tsum;
#pragma unroll
  for (int off = 1; off < 64; off <<= 1) {
    int nv = __shfl_up(incl, off);
    if (lane >= off) incl += nv;
  }
  __shared__ int wsum[4];
  if (lane == 63) wsum[wv] = incl;
  __syncthreads();
  int woff = 0;
  for (int w = 0; w < wv; ++w) woff += wsum[w];
  int run = woff + incl - tsum;
#pragma unroll
  for (int i = 0; i < 8; ++i) {
    int idx = tbase + i;
    if (idx < N) row_ptr[idx] = run;
    run += vals[i];
  }
  if (threadIdx.x == 255) bsum[blockIdx.x] = woff + incl;
}

__global__ __launch_bounds__(64) void scan2_kernel(
    const int* __restrict__ bsum, int* __restrict__ bpre, int NB) {
  const int lane = threadIdx.x;
  int running = 0;
  for (int c = 0; c < NB; c += 64) {
    int v = (c + lane < NB) ? bsum[c + lane] : 0;
    int incl = v;
#pragma unroll
    for (int off = 1; off < 64; off <<= 1) {
      int nv = __shfl_up(incl, off);
      if (lane >= off) incl += nv;
    }
    if (c + lane < NB) bpre[c + lane] = running + incl - v;
    running += __shfl(incl, 63);
  }
}

__global__ __launch_bounds__(256) void scan3_kernel(
    int* __restrict__ row_ptr, const int* __restrict__ bpre, int N, int E) {
  int t = blockIdx.x * 256 + threadIdx.x;
  if (t < N) row_ptr[t] += bpre[t >> 11];
  if (t == 0) row_ptr[N] = E;
}

__global__ __launch_bounds__(256) void scatter_kernel(
    const int* __restrict__ src, const int* __restrict__ dst,
    const int* __restrict__ row_ptr, int* __restrict__ cursor,
    int* __restrict__ ssorted, int E) {
  int e = blockIdx.x * 256 + threadIdx.x;
  if (e >= E) return;
  int d = dst[e];
  int pos = row_ptr[d] + atomicAdd(&cursor[d], 1);
  ssorted[pos] = src[e];
}

// ===================== attention scores ==========================
__global__ __launch_bounds__(256) void scores_kernel(
    const bf16* __restrict__ feat, const float* __restrict__ attn_l,
    const float* __restrict__ attn_r, float* __restrict__ el,
    float* __restrict__ er, int N) {
  int t = blockIdx.x * 256 + threadIdx.x;
  if (t >= N * HEADS) return;
  int h = t & 3;
  const bf16x2* f2 = (const bf16x2*)(feat + (size_t)t * OUTF);
  const float* al = attn_l + h * OUTF;
  const float* ar = attn_r + h * OUTF;
  float sl = 0.f, sr = 0.f;
#pragma unroll
  for (int k = 0; k < OUTF / 2; ++k) {
    float2 v = __bfloat1622float2(f2[k]);
    sl = fmaf(v.x, al[2 * k], sl);
    sl = fmaf(v.y, al[2 * k + 1], sl);
    sr = fmaf(v.x, ar[2 * k], sr);
    sr = fmaf(v.y, ar[2 * k + 1], sr);
  }
  el[t] = sl;
  er[t] = sr;
}

// ============ fused softmax + aggregate (single edge pass) =================
// One wave per node; lane holds cols (2*lane, 2*lane+1), head h = lane>>4.
// 4-edge straight-line unroll: 12 independent gathers in flight per wave.
// alpha = exp(v)/sum(exp) without max-subtraction (v bounded).
// Layer 1 epilogue: B[n] = elu(inv*agg + B[n] + bias)   (in place)
__global__ __launch_bounds__(256) void agg1_fused(
    const int* __restrict__ row_ptr, const int* __restrict__ ssorted,
    const float* __restrict__ el, const float* __restrict__ er,
    const bf16* __restrict__ feat, float* __restrict__ B,
    const float* __restrict__ bias, int N) {
  int n = blockIdx.x * 4 + (threadIdx.x >> 6);
  if (n >= N) return;
  const int lane = threadIdx.x & 63;
  const int c2 = lane * 2, h = lane >> 4;
  const int rb = row_ptr[n], re = row_ptr[n + 1];
  const float ern = er[n * HEADS + h];

  float ax = 0.f, ay = 0.f, ssum = 0.f;
  int e = rb;
  for (; e + 3 < re; e += 4) {
    int s0 = ssorted[e], s1 = ssorted[e + 1];
    int s2 = ssorted[e + 2], s3 = ssorted[e + 3];
    float x0 = __expf(lrelu(el[s0 * HEADS + h] + ern));
    float x1 = __expf(lrelu(el[s1 * HEADS + h] + ern));
    float x2 = __expf(lrelu(el[s2 * HEADS + h] + ern));
    float x3 = __expf(lrelu(el[s3 * HEADS + h] + ern));
    float2 f0 = unpack_bf16(*(const unsigned*)&feat[(size_t)s0 * HF + c2]);
    float2 f1 = unpack_bf16(*(const unsigned*)&feat[(size_t)s1 * HF + c2]);
    float2 f2 = unpack_bf16(*(const unsigned*)&feat[(size_t)s2 * HF + c2]);
    float2 f3 = unpack_bf16(*(const unsigned*)&feat[(size_t)s3 * HF + c2]);
    ssum += (x0 + x1) + (x2 + x3);
    ax = fmaf(x0, f0.x, ax); ay = fmaf(x0, f0.y, ay);
    ax = fmaf(x1, f1.x, ax); ay = fmaf(x1, f1.y, ay);
    ax = fmaf(x2, f2.x, ax); ay = fmaf(x2, f2.y, ay);
    ax = fmaf(x3, f3.x, ax); ay = fmaf(x3, f3.y, ay);
  }
  for (; e < re; ++e) {
    int s = ssorted[e];
    float x = __expf(lrelu(el[s * HEADS + h] + ern));
    float2 f = unpack_bf16(*(const unsigned*)&feat[(size_t)s * HF + c2]);
    ssum += x;
    ax = fmaf(x, f.x, ax); ay = fmaf(x, f.y, ay);
  }
  float inv = 1.f / ssum;
  float2 r = *(const float2*)&B[(size_t)n * HF + c2];
  float2 bi = *(const float2*)&bias[c2];
  float vx = fmaf(ax, inv, r.x + bi.x);
  float vy = fmaf(ay, inv, r.y + bi.y);
  vx = (vx > 0.f) ? vx : expm1f(vx);
  vy = (vy > 0.f) ? vy : expm1f(vy);
  *(float2*)&B[(size_t)n * HF + c2] = make_float2(vx, vy);
}

// Layer 2 epilogue: head-mean -> sigmoid gate -> readout atomics.
__global__ __launch_bounds__(256) void agg2_fused(
    const int* __restrict__ row_ptr, const int* __restrict__ ssorted,
    const float* __restrict__ el, const float* __restrict__ er,
    const bf16* __restrict__ feat, const float* __restrict__ h1,
    const float* __restrict__ bias, const float* __restrict__ ww,
    const float* __restrict__ wb, const int* __restrict__ gids,
    float* __restrict__ hsum, unsigned* __restrict__ hmax, int N) {
  int n = blockIdx.x * 4 + (threadIdx.x >> 6);
  if (n >= N) return;
  const int lane = threadIdx.x & 63;
  const int c2 = lane * 2, h = lane >> 4;
  const int rb = row_ptr[n], re = row_ptr[n + 1];
  const float ern = er[n * HEADS + h];

  float ax = 0.f, ay = 0.f, ssum = 0.f;
  int e = rb;
  for (; e + 3 < re; e += 4) {
    int s0 = ssorted[e], s1 = ssorted[e + 1];
    int s2 = ssorted[e + 2], s3 = ssorted[e + 3];
    float x0 = __expf(lrelu(el[s0 * HEADS + h] + ern));
    float x1 = __expf(lrelu(el[s1 * HEADS + h] + ern));
    float x2 = __expf(lrelu(el[s2 * HEADS + h] + ern));
    float x3 = __expf(lrelu(el[s3 * HEADS + h] + ern));
    float2 f0 = unpack_bf16(*(const unsigned*)&feat[(size_t)s0 * HF + c2]);
    float2 f1 = unpack_bf16(*(const unsigned*)&feat[(size_t)s1 * HF + c2]);
    float2 f2 = unpack_bf16(*(const unsigned*)&feat[(size_t)s2 * HF + c2]);
    float2 f3 = unpack_bf16(*(const unsigned*)&feat[(size_t)s3 * HF + c2]);
    ssum += (x0 + x1) + (x2 + x3);
    ax = fmaf(x0, f0.x, ax); ay = fmaf(x0, f0.y, ay);
    ax = fmaf(x1, f1.x, ax); ay = fmaf(x1, f1.y, ay);
    ax = fmaf(x2, f2.x, ax); ay = fmaf(x2, f2.y, ay);
    ax = fmaf(x3, f3.x, ax); ay = fmaf(x3, f3.y, ay);
  }
  for (; e < re; ++e) {
    int s = ssorted[e];
    float x = __expf(lrelu(el[s * HEADS + h] + ern));
    float2 f = unpack_bf16(*(const unsigned*)&feat[(size_t)s * HF + c2]);
    ssum += x;
    ax = fmaf(x, f.x, ax); ay = fmaf(x, f.y, ay);
  }
  float inv = 1.f / ssum;
  float2 r = *(const float2*)&h1[(size_t)n * HF + c2];
  float2 bi = *(const float2*)&bias[c2];
  ax = fmaf(ax, inv, r.x + bi.x);
  ay = fmaf(ay, inv, r.y + bi.y);
  // head mean: after xor 16,32 every lane holds the sum over its 4-head class
#pragma unroll
  for (int off = 16; off < 64; off <<= 1) {
    ax += __shfl_xor(ax, off);
    ay += __shfl_xor(ay, off);
  }
  ax *= 0.25f;
  ay *= 0.25f;
  // sigmoid gate: dot(node_feats, ww) reduced over the 16-lane col groups
  int c = c2 & 31;
  float d = fmaf(ax, ww[c], ay * ww[c + 1]);
#pragma unroll
  for (int off = 1; off < 16; off <<= 1) d += __shfl_xor(d, off);
  float wv = 1.f / (1.f + __expf(-(d + wb[0])));
  if (lane < 16) {
    int g = gids[n];
    atomicAdd(&hsum[g * OUTF + c], wv * ax);
    atomicAdd(&hsum[g * OUTF + c + 1], wv * ay);
    atomicMax(&hmax[g * OUTF + c], enc_f(ax));
    atomicMax(&hmax[g * OUTF + c + 1], enc_f(ay));
  }
}

// ============================ readout tail =================================
__global__ __launch_bounds__(256) void init_readout_kernel(
    float* __restrict__ hsum, unsigned* __restrict__ hmax, int g32) {
  int t = blockIdx.x * 256 + threadIdx.x;
  if (t >= g32) return;
  hsum[t] = 0.f;
  hmax[t] = NEG_INF_ENC;
}

__global__ __launch_bounds__(256) void final_gemm_kernel(
    const float* __restrict__ hsum, const unsigned* __restrict__ hmax,
    const float* __restrict__ tw, const float* __restrict__ tb,
    float* __restrict__ out, int G) {
  __shared__ float tws[64 * PRED_DIM];
  for (int i = threadIdx.x; i < 64 * PRED_DIM; i += 256) tws[i] = tw[i];
  __syncthreads();
  int g = blockIdx.x * 2 + (threadIdx.x >> 7);
  int p = threadIdx.x & 127;
  if (g >= G) return;
  float acc = tb[p];
#pragma unroll
  for (int k = 0; k < OUTF; ++k)
    acc = fmaf(hsum[g * OUTF + k], tws[k * PRED_DIM + p], acc);
#pragma unroll
  for (int k = 0; k < OUTF; ++k)
    acc = fmaf(dec_f(hmax[g * OUTF + k]), tws[(OUTF + k) * PRED_DIM + p], acc);
  out[(size_t)g * PRED_DIM + p] = acc;
}

static inline int cdiv(long long a, int b) { return (int)((a + b - 1) / b); }

extern "C" void kernel_launch(void* const* d_in, const int* in_sizes, int n_in,
                              void* d_out, int out_size, void* d_ws,
                              size_t ws_size, hipStream_t stream) {
  const float* feats   = (const float*)d_in[0];
  const int*   src     = (const int*)d_in[1];
  const int*   dst     = (const int*)d_in[2];
  const int*   gids    = (const int*)d_in[3];
  const float* fc1_w   = (const float*)d_in[4];
  const float* attn_l1 = (const float*)d_in[5];
  const float* attn_r1 = (const float*)d_in[6];
  const float* res1_w  = (const float*)d_in[7];
  const float* bias1   = (const float*)d_in[8];
  const float* fc2_w   = (const float*)d_in[9];
  const float* attn_l2 = (const float*)d_in[10];
  const float* attn_r2 = (const float*)d_in[11];
  const float* bias2   = (const float*)d_in[12];
  const float* ww      = (const float*)d_in[13];
  const float* wb      = (const float*)d_in[14];
  const float* tw      = (const float*)d_in[15];
  const float* tb      = (const float*)d_in[16];
  float* out = (float*)d_out;

  const int N = in_sizes[0] / IN_FEATS;  // 100000
  const int E = in_sizes[1];             // 900000
  const int G = out_size / PRED_DIM;     // 2048
  const int NB = cdiv(N, 2048);

  // ---- workspace layout ----
  bf16* A = (bf16*)d_ws;                                   // N*128 bf16
  float* B  = (float*)((char*)d_ws + (size_t)N * HF * 2);  // N*128 f32
  float* el = B + (size_t)N * HF;        // N*4
  float* er = el + (size_t)N * HEADS;    // N*4
  float* hsum = er + (size_t)N * HEADS;  // G*32
  unsigned* hmax = (unsigned*)(hsum + (size_t)G * OUTF);   // G*32
  int* deg     = (int*)(hmax + (size_t)G * OUTF);  // N
  int* cursor  = deg + N;                          // N
  int* row_ptr = cursor + N;                       // N+1
  int* ssorted = row_ptr + (N + 1);                // E
  int* bsum    = ssorted + E;                      // NB
  int* bpre    = bsum + NB;                        // NB

  const int n4 = N * HEADS;
  const int gblk = cdiv(N, 64);
  const int nwblk = cdiv(N, 4);

  // ===================== CSR build =====================
  hipMemsetAsync(deg, 0, (size_t)N * sizeof(int), stream);
  hipMemsetAsync(cursor, 0, (size_t)N * sizeof(int), stream);
  hist_kernel<<<cdiv(E, 256), 256, 0, stream>>>(dst, deg, E);
  scan1_kernel<<<NB, 256, 0, stream>>>(deg, row_ptr, bsum, N);
  scan2_kernel<<<1, 64, 0, stream>>>(bsum, bpre, NB);
  scan3_kernel<<<cdiv(N, 256), 256, 0, stream>>>(row_ptr, bpre, N, E);
  scatter_kernel<<<cdiv(E, 256), 256, 0, stream>>>(src, dst, row_ptr, cursor,
                                                   ssorted, E);

  // ===================== Layer 1 =====================
  gemm_tiled<IN_FEATS, true><<<gblk, 256, 0, stream>>>(feats, fc1_w, A, N);
  gemm_tiled<IN_FEATS, false><<<gblk, 256, 0, stream>>>(feats, res1_w, B, N);
  scores_kernel<<<cdiv(n4, 256), 256, 0, stream>>>(A, attn_l1, attn_r1, el, er, N);
  agg1_fused<<<nwblk, 256, 0, stream>>>(row_ptr, ssorted, el, er, A, B, bias1, N);

  // ===================== Layer 2 =====================
  gemm_tiled<HF, true><<<gblk, 256, 0, stream>>>(B, fc2_w, A, N);
  scores_kernel<<<cdiv(n4, 256), 256, 0, stream>>>(A, attn_l2, attn_r2, el, er, N);
  init_readout_kernel<<<cdiv(G * OUTF, 256), 256, 0, stream>>>(hsum, hmax,
                                                               G * OUTF);
  agg2_fused<<<nwblk, 256, 0, stream>>>(row_ptr, ssorted, el, er, A, B, bias2,
                                        ww, wb, gids, hsum, hmax, N);

  // ===================== Readout =====================
  final_gemm_kernel<<<cdiv(G, 2), 256, 0, stream>>>(hsum, hmax, tw, tb, out, G);
}

// Round 8
// 480.281 us; speedup vs baseline: 1.1382x; 1.0662x over previous
//
#include <hip/hip_runtime.h>
#include <hip/hip_bf16.h>

// ---------------------------------------------------------------------------
// DGL GAT (2-layer, heads=4, out=32) + WeightedSumAndMax readout.
// Round 7: residual/h1 path stored bf16 (saves ~150MB of f32 traffic);
//          attention scores el/er computed in the GEMM epilogue via
//          xor-shuffle reduction (scores kernels deleted). Agg loop body
//          unchanged from round 6 (proven 4-edge straight-line unroll).
// ---------------------------------------------------------------------------

#define HEADS 4
#define OUTF 32
#define HF 128            // HEADS*OUTF
#define IN_FEATS 74
#define PRED_DIM 128
#define NEG_SLOPE 0.2f
#define NEG_INF_ENC 0x007fffffu   // enc_f(-inf)

typedef __hip_bfloat16 bf16;
typedef __hip_bfloat162 bf16x2;

__device__ __forceinline__ unsigned enc_f(float f) {
  unsigned u = __float_as_uint(f);
  return (u & 0x80000000u) ? ~u : (u | 0x80000000u);
}
__device__ __forceinline__ float dec_f(unsigned k) {
  return (k & 0x80000000u) ? __uint_as_float(k & 0x7fffffffu)
                           : __uint_as_float(~k);
}
__device__ __forceinline__ unsigned pack_bf16(float a, float b) {
  bf16x2 h = __float22bfloat162_rn(make_float2(a, b));
  return *(unsigned*)&h;
}
__device__ __forceinline__ float2 unpack_bf16(unsigned u) {
  bf16x2 h = *(bf16x2*)&u;
  return __bfloat1622float2(h);
}
__device__ __forceinline__ float lrelu(float v) {
  return (v >= 0.f) ? v : NEG_SLOPE * v;
}
__device__ __forceinline__ float ld_f(const float* p) { return *p; }
__device__ __forceinline__ float ld_f(const bf16* p) {
  return __bfloat162float(*p);
}

// ========================= node GEMM =============================
// out[n][j] = dot(X[n,:K], W[:K,j]), bf16 output. 64 nodes x 128 cols/block,
// 8x4 per thread. SCORES: fused el/er epilogue (thread's 4 cols are one
// head; xor-shuffle(1,2,4) reduces the 8 threads sharing (node, head)).
template <int K, typename XT, bool SCORES>
__global__ __launch_bounds__(256) void gemm_tiled(
    const XT* __restrict__ X, const float* __restrict__ W,
    const float* __restrict__ attn_l, const float* __restrict__ attn_r,
    bf16* __restrict__ out, float* __restrict__ el, float* __restrict__ er,
    int N) {
  constexpr int BK = 32;
  constexpr int APAD = 68;
  __shared__ float as[BK * APAD];
  __shared__ float bs[BK * HF];
  const int tid = threadIdx.x;
  const int tx = tid & 31;
  const int ty = tid >> 5;
  const int j4 = tx * 4;
  const int nb = ty * 8;
  const int n0 = blockIdx.x * 64;

  float acc[8][4] = {};
  for (int k0 = 0; k0 < K; k0 += BK) {
#pragma unroll
    for (int i = 0; i < 8; ++i) {
      int idx = i * 256 + tid;
      int kk = idx & 31, nl = idx >> 5;
      int n = n0 + nl, k = k0 + kk;
      float v = 0.f;
      if (n < N && k < K) v = ld_f(&X[(size_t)n * K + k]);
      as[kk * APAD + nl] = v;
    }
#pragma unroll
    for (int i = 0; i < 16; ++i) {
      int idx = i * 256 + tid;
      int kk = idx >> 7, c = idx & 127;
      int k = k0 + kk;
      bs[idx] = (k < K) ? W[(size_t)k * HF + c] : 0.f;
    }
    __syncthreads();
#pragma unroll 8
    for (int kk = 0; kk < BK; ++kk) {
      float4 wv = *(const float4*)&bs[kk * HF + j4];
      float4 a0 = *(const float4*)&as[kk * APAD + nb];
      float4 a1 = *(const float4*)&as[kk * APAD + nb + 4];
      float av[8] = {a0.x, a0.y, a0.z, a0.w, a1.x, a1.y, a1.z, a1.w};
#pragma unroll
      for (int i = 0; i < 8; ++i) {
        acc[i][0] = fmaf(av[i], wv.x, acc[i][0]);
        acc[i][1] = fmaf(av[i], wv.y, acc[i][1]);
        acc[i][2] = fmaf(av[i], wv.z, acc[i][2]);
        acc[i][3] = fmaf(av[i], wv.w, acc[i][3]);
      }
    }
    __syncthreads();
  }
#pragma unroll
  for (int i = 0; i < 8; ++i) {
    int n = n0 + nb + i;
    if (n < N)
      *(uint2*)&out[(size_t)n * HF + j4] =
          make_uint2(pack_bf16(acc[i][0], acc[i][1]),
                     pack_bf16(acc[i][2], acc[i][3]));
  }
  if (SCORES) {
    float al0 = attn_l[j4], al1 = attn_l[j4 + 1];
    float al2 = attn_l[j4 + 2], al3 = attn_l[j4 + 3];
    float ar0 = attn_r[j4], ar1 = attn_r[j4 + 1];
    float ar2 = attn_r[j4 + 2], ar3 = attn_r[j4 + 3];
    const int h = tx >> 3;
#pragma unroll
    for (int i = 0; i < 8; ++i) {
      float pl = acc[i][0] * al0 + acc[i][1] * al1 +
                 acc[i][2] * al2 + acc[i][3] * al3;
      float pr = acc[i][0] * ar0 + acc[i][1] * ar1 +
                 acc[i][2] * ar2 + acc[i][3] * ar3;
      pl += __shfl_xor(pl, 1); pr += __shfl_xor(pr, 1);
      pl += __shfl_xor(pl, 2); pr += __shfl_xor(pr, 2);
      pl += __shfl_xor(pl, 4); pr += __shfl_xor(pr, 4);
      int n = n0 + nb + i;
      if ((tx & 7) == 0 && n < N) {
        el[n * HEADS + h] = pl;
        er[n * HEADS + h] = pr;
      }
    }
  }
}

// ============================ CSR build ====================================
__global__ __launch_bounds__(256) void hist_kernel(
    const int* __restrict__ dst, int* __restrict__ deg, int E) {
  int e = blockIdx.x * 256 + threadIdx.x;
  if (e < E) atomicAdd(&deg[dst[e]], 1);
}

__global__ __launch_bounds__(256) void scan1_kernel(
    const int* __restrict__ deg, int* __restrict__ row_ptr,
    int* __restrict__ bsum, int N) {
  const int base = blockIdx.x * 2048;
  const int tbase = base + threadIdx.x * 8;
  int vals[8];
  int tsum = 0;
#pragma unroll
  for (int i = 0; i < 8; ++i) {
    int idx = tbase + i;
    vals[i] = (idx < N) ? deg[idx] : 0;
    tsum += vals[i];
  }
  const int lane = threadIdx.x & 63, wv = threadIdx.x >> 6;
  int incl = tsum;
#pragma unroll
  for (int off = 1; off < 64; off <<= 1) {
    int nv = __shfl_up(incl, off);
    if (lane >= off) incl += nv;
  }
  __shared__ int wsum[4];
  if (lane == 63) wsum[wv] = incl;
  __syncthreads();
  int woff = 0;
  for (int w = 0; w < wv; ++w) woff += wsum[w];
  int run = woff + incl - tsum;
#pragma unroll
  for (int i = 0; i < 8; ++i) {
    int idx = tbase + i;
    if (idx < N) row_ptr[idx] = run;
    run += vals[i];
  }
  if (threadIdx.x == 255) bsum[blockIdx.x] = woff + incl;
}

__global__ __launch_bounds__(64) void scan2_kernel(
    const int* __restrict__ bsum, int* __restrict__ bpre, int NB) {
  const int lane = threadIdx.x;
  int running = 0;
  for (int c = 0; c < NB; c += 64) {
    int v = (c + lane < NB) ? bsum[c + lane] : 0;
    int incl = v;
#pragma unroll
    for (int off = 1; off < 64; off <<= 1) {
      int nv = __shfl_up(incl, off);
      if (lane >= off) incl += nv;
    }
    if (c + lane < NB) bpre[c + lane] = running + incl - v;
    running += __shfl(incl, 63);
  }
}

__global__ __launch_bounds__(256) void scan3_kernel(
    int* __restrict__ row_ptr, const int* __restrict__ bpre, int N, int E) {
  int t = blockIdx.x * 256 + threadIdx.x;
  if (t < N) row_ptr[t] += bpre[t >> 11];
  if (t == 0) row_ptr[N] = E;
}

__global__ __launch_bounds__(256) void scatter_kernel(
    const int* __restrict__ src, const int* __restrict__ dst,
    const int* __restrict__ row_ptr, int* __restrict__ cursor,
    int* __restrict__ ssorted, int E) {
  int e = blockIdx.x * 256 + threadIdx.x;
  if (e >= E) return;
  int d = dst[e];
  int pos = row_ptr[d] + atomicAdd(&cursor[d], 1);
  ssorted[pos] = src[e];
}

// ============ fused softmax + aggregate (single edge pass) =================
// One wave per node; lane holds cols (2*lane, 2*lane+1), head h = lane>>4.
// 4-edge straight-line unroll. alpha = exp(v)/sum(exp), no max-subtraction.
// Layer 1 epilogue: H[n] = elu(inv*agg + res[n] + bias)   (res, H bf16)
__global__ __launch_bounds__(256) void agg1_fused(
    const int* __restrict__ row_ptr, const int* __restrict__ ssorted,
    const float* __restrict__ el, const float* __restrict__ er,
    const bf16* __restrict__ feat, const bf16* __restrict__ res,
    bf16* __restrict__ H, const float* __restrict__ bias, int N) {
  int n = blockIdx.x * 4 + (threadIdx.x >> 6);
  if (n >= N) return;
  const int lane = threadIdx.x & 63;
  const int c2 = lane * 2, h = lane >> 4;
  const int rb = row_ptr[n], re = row_ptr[n + 1];
  const float ern = er[n * HEADS + h];

  float ax = 0.f, ay = 0.f, ssum = 0.f;
  int e = rb;
  for (; e + 3 < re; e += 4) {
    int s0 = ssorted[e], s1 = ssorted[e + 1];
    int s2 = ssorted[e + 2], s3 = ssorted[e + 3];
    float x0 = __expf(lrelu(el[s0 * HEADS + h] + ern));
    float x1 = __expf(lrelu(el[s1 * HEADS + h] + ern));
    float x2 = __expf(lrelu(el[s2 * HEADS + h] + ern));
    float x3 = __expf(lrelu(el[s3 * HEADS + h] + ern));
    float2 f0 = unpack_bf16(*(const unsigned*)&feat[(size_t)s0 * HF + c2]);
    float2 f1 = unpack_bf16(*(const unsigned*)&feat[(size_t)s1 * HF + c2]);
    float2 f2 = unpack_bf16(*(const unsigned*)&feat[(size_t)s2 * HF + c2]);
    float2 f3 = unpack_bf16(*(const unsigned*)&feat[(size_t)s3 * HF + c2]);
    ssum += (x0 + x1) + (x2 + x3);
    ax = fmaf(x0, f0.x, ax); ay = fmaf(x0, f0.y, ay);
    ax = fmaf(x1, f1.x, ax); ay = fmaf(x1, f1.y, ay);
    ax = fmaf(x2, f2.x, ax); ay = fmaf(x2, f2.y, ay);
    ax = fmaf(x3, f3.x, ax); ay = fmaf(x3, f3.y, ay);
  }
  for (; e < re; ++e) {
    int s = ssorted[e];
    float x = __expf(lrelu(el[s * HEADS + h] + ern));
    float2 f = unpack_bf16(*(const unsigned*)&feat[(size_t)s * HF + c2]);
    ssum += x;
    ax = fmaf(x, f.x, ax); ay = fmaf(x, f.y, ay);
  }
  float inv = 1.f / ssum;
  float2 r = unpack_bf16(*(const unsigned*)&res[(size_t)n * HF + c2]);
  float2 bi = *(const float2*)&bias[c2];
  float vx = fmaf(ax, inv, r.x + bi.x);
  float vy = fmaf(ay, inv, r.y + bi.y);
  vx = (vx > 0.f) ? vx : expm1f(vx);
  vy = (vy > 0.f) ? vy : expm1f(vy);
  *(unsigned*)&H[(size_t)n * HF + c2] = pack_bf16(vx, vy);
}

// Layer 2 epilogue: head-mean -> sigmoid gate -> readout atomics.
__global__ __launch_bounds__(256) void agg2_fused(
    const int* __restrict__ row_ptr, const int* __restrict__ ssorted,
    const float* __restrict__ el, const float* __restrict__ er,
    const bf16* __restrict__ feat, const bf16* __restrict__ h1,
    const float* __restrict__ bias, const float* __restrict__ ww,
    const float* __restrict__ wb, const int* __restrict__ gids,
    float* __restrict__ hsum, unsigned* __restrict__ hmax, int N) {
  int n = blockIdx.x * 4 + (threadIdx.x >> 6);
  if (n >= N) return;
  const int lane = threadIdx.x & 63;
  const int c2 = lane * 2, h = lane >> 4;
  const int rb = row_ptr[n], re = row_ptr[n + 1];
  const float ern = er[n * HEADS + h];

  float ax = 0.f, ay = 0.f, ssum = 0.f;
  int e = rb;
  for (; e + 3 < re; e += 4) {
    int s0 = ssorted[e], s1 = ssorted[e + 1];
    int s2 = ssorted[e + 2], s3 = ssorted[e + 3];
    float x0 = __expf(lrelu(el[s0 * HEADS + h] + ern));
    float x1 = __expf(lrelu(el[s1 * HEADS + h] + ern));
    float x2 = __expf(lrelu(el[s2 * HEADS + h] + ern));
    float x3 = __expf(lrelu(el[s3 * HEADS + h] + ern));
    float2 f0 = unpack_bf16(*(const unsigned*)&feat[(size_t)s0 * HF + c2]);
    float2 f1 = unpack_bf16(*(const unsigned*)&feat[(size_t)s1 * HF + c2]);
    float2 f2 = unpack_bf16(*(const unsigned*)&feat[(size_t)s2 * HF + c2]);
    float2 f3 = unpack_bf16(*(const unsigned*)&feat[(size_t)s3 * HF + c2]);
    ssum += (x0 + x1) + (x2 + x3);
    ax = fmaf(x0, f0.x, ax); ay = fmaf(x0, f0.y, ay);
    ax = fmaf(x1, f1.x, ax); ay = fmaf(x1, f1.y, ay);
    ax = fmaf(x2, f2.x, ax); ay = fmaf(x2, f2.y, ay);
    ax = fmaf(x3, f3.x, ax); ay = fmaf(x3, f3.y, ay);
  }
  for (; e < re; ++e) {
    int s = ssorted[e];
    float x = __expf(lrelu(el[s * HEADS + h] + ern));
    float2 f = unpack_bf16(*(const unsigned*)&feat[(size_t)s * HF + c2]);
    ssum += x;
    ax = fmaf(x, f.x, ax); ay = fmaf(x, f.y, ay);
  }
  float inv = 1.f / ssum;
  float2 r = unpack_bf16(*(const unsigned*)&h1[(size_t)n * HF + c2]);
  float2 bi = *(const float2*)&bias[c2];
  ax = fmaf(ax, inv, r.x + bi.x);
  ay = fmaf(ay, inv, r.y + bi.y);
  // head mean: after xor 16,32 every lane holds the sum over its 4-head class
#pragma unroll
  for (int off = 16; off < 64; off <<= 1) {
    ax += __shfl_xor(ax, off);
    ay += __shfl_xor(ay, off);
  }
  ax *= 0.25f;
  ay *= 0.25f;
  // sigmoid gate: dot(node_feats, ww) reduced over the 16-lane col groups
  int c = c2 & 31;
  float d = fmaf(ax, ww[c], ay * ww[c + 1]);
#pragma unroll
  for (int off = 1; off < 16; off <<= 1) d += __shfl_xor(d, off);
  float wv = 1.f / (1.f + __expf(-(d + wb[0])));
  if (lane < 16) {
    int g = gids[n];
    atomicAdd(&hsum[g * OUTF + c], wv * ax);
    atomicAdd(&hsum[g * OUTF + c + 1], wv * ay);
    atomicMax(&hmax[g * OUTF + c], enc_f(ax));
    atomicMax(&hmax[g * OUTF + c + 1], enc_f(ay));
  }
}

// ============================ readout tail =================================
__global__ __launch_bounds__(256) void init_readout_kernel(
    float* __restrict__ hsum, unsigned* __restrict__ hmax, int g32) {
  int t = blockIdx.x * 256 + threadIdx.x;
  if (t >= g32) return;
  hsum[t] = 0.f;
  hmax[t] = NEG_INF_ENC;
}

__global__ __launch_bounds__(256) void final_gemm_kernel(
    const float* __restrict__ hsum, const unsigned* __restrict__ hmax,
    const float* __restrict__ tw, const float* __restrict__ tb,
    float* __restrict__ out, int G) {
  __shared__ float tws[64 * PRED_DIM];
  for (int i = threadIdx.x; i < 64 * PRED_DIM; i += 256) tws[i] = tw[i];
  __syncthreads();
  int g = blockIdx.x * 2 + (threadIdx.x >> 7);
  int p = threadIdx.x & 127;
  if (g >= G) return;
  float acc = tb[p];
#pragma unroll
  for (int k = 0; k < OUTF; ++k)
    acc = fmaf(hsum[g * OUTF + k], tws[k * PRED_DIM + p], acc);
#pragma unroll
  for (int k = 0; k < OUTF; ++k)
    acc = fmaf(dec_f(hmax[g * OUTF + k]), tws[(OUTF + k) * PRED_DIM + p], acc);
  out[(size_t)g * PRED_DIM + p] = acc;
}

static inline int cdiv(long long a, int b) { return (int)((a + b - 1) / b); }

extern "C" void kernel_launch(void* const* d_in, const int* in_sizes, int n_in,
                              void* d_out, int out_size, void* d_ws,
                              size_t ws_size, hipStream_t stream) {
  const float* feats   = (const float*)d_in[0];
  const int*   src     = (const int*)d_in[1];
  const int*   dst     = (const int*)d_in[2];
  const int*   gids    = (const int*)d_in[3];
  const float* fc1_w   = (const float*)d_in[4];
  const float* attn_l1 = (const float*)d_in[5];
  const float* attn_r1 = (const float*)d_in[6];
  const float* res1_w  = (const float*)d_in[7];
  const float* bias1   = (const float*)d_in[8];
  const float* fc2_w   = (const float*)d_in[9];
  const float* attn_l2 = (const float*)d_in[10];
  const float* attn_r2 = (const float*)d_in[11];
  const float* bias2   = (const float*)d_in[12];
  const float* ww      = (const float*)d_in[13];
  const float* wb      = (const float*)d_in[14];
  const float* tw      = (const float*)d_in[15];
  const float* tb      = (const float*)d_in[16];
  float* out = (float*)d_out;

  const int N = in_sizes[0] / IN_FEATS;  // 100000
  const int E = in_sizes[1];             // 900000
  const int G = out_size / PRED_DIM;     // 2048
  const int NB = cdiv(N, 2048);

  // ---- workspace layout ----
  bf16* A = (bf16*)d_ws;                      // N*128 bf16 (feat1/feat2)
  bf16* B = A + (size_t)N * HF;               // N*128 bf16 (res1)
  bf16* H = B + (size_t)N * HF;               // N*128 bf16 (h1)
  float* el = (float*)(H + (size_t)N * HF);   // N*4
  float* er = el + (size_t)N * HEADS;         // N*4
  float* hsum = er + (size_t)N * HEADS;       // G*32
  unsigned* hmax = (unsigned*)(hsum + (size_t)G * OUTF);  // G*32
  int* deg     = (int*)(hmax + (size_t)G * OUTF);  // N
  int* cursor  = deg + N;                          // N
  int* row_ptr = cursor + N;                       // N+1
  int* ssorted = row_ptr + (N + 1);                // E
  int* bsum    = ssorted + E;                      // NB
  int* bpre    = bsum + NB;                        // NB

  const int gblk = cdiv(N, 64);
  const int nwblk = cdiv(N, 4);

  // ===================== CSR build =====================
  hipMemsetAsync(deg, 0, (size_t)N * sizeof(int), stream);
  hipMemsetAsync(cursor, 0, (size_t)N * sizeof(int), stream);
  hist_kernel<<<cdiv(E, 256), 256, 0, stream>>>(dst, deg, E);
  scan1_kernel<<<NB, 256, 0, stream>>>(deg, row_ptr, bsum, N);
  scan2_kernel<<<1, 64, 0, stream>>>(bsum, bpre, NB);
  scan3_kernel<<<cdiv(N, 256), 256, 0, stream>>>(row_ptr, bpre, N, E);
  scatter_kernel<<<cdiv(E, 256), 256, 0, stream>>>(src, dst, row_ptr, cursor,
                                                   ssorted, E);

  // ===================== Layer 1 =====================
  gemm_tiled<IN_FEATS, float, true><<<gblk, 256, 0, stream>>>(
      feats, fc1_w, attn_l1, attn_r1, A, el, er, N);
  gemm_tiled<IN_FEATS, float, false><<<gblk, 256, 0, stream>>>(
      feats, res1_w, nullptr, nullptr, B, nullptr, nullptr, N);
  agg1_fused<<<nwblk, 256, 0, stream>>>(row_ptr, ssorted, el, er, A, B, H,
                                        bias1, N);

  // ===================== Layer 2 =====================
  gemm_tiled<HF, bf16, true><<<gblk, 256, 0, stream>>>(
      H, fc2_w, attn_l2, attn_r2, A, el, er, N);
  init_readout_kernel<<<cdiv(G * OUTF, 256), 256, 0, stream>>>(hsum, hmax,
                                                               G * OUTF);
  agg2_fused<<<nwblk, 256, 0, stream>>>(row_ptr, ssorted, el, er, A, H, bias2,
                                        ww, wb, gids, hsum, hmax, N);

  // ===================== Readout =====================
  final_gemm_kernel<<<cdiv(G, 2), 256, 0, stream>>>(hsum, hmax, tw, tb, out, G);
}

// Round 9
// 477.019 us; speedup vs baseline: 1.1460x; 1.0068x over previous
//
#include <hip/hip_runtime.h>
#include <hip/hip_bf16.h>

// ---------------------------------------------------------------------------
// DGL GAT (2-layer, heads=4, out=32) + WeightedSumAndMax readout.
// Round 8: agg main loop deepened to 8-edge straight-line unroll (~24 loads
//          in flight/wave; round 5/6 showed unroll depth is the lever for
//          this latency-bound gather loop); lrelu as fmaxf(v, 0.2v).
//          Everything else unchanged from round 7.
// ---------------------------------------------------------------------------

#define HEADS 4
#define OUTF 32
#define HF 128            // HEADS*OUTF
#define IN_FEATS 74
#define PRED_DIM 128
#define NEG_SLOPE 0.2f
#define NEG_INF_ENC 0x007fffffu   // enc_f(-inf)

typedef __hip_bfloat16 bf16;
typedef __hip_bfloat162 bf16x2;

__device__ __forceinline__ unsigned enc_f(float f) {
  unsigned u = __float_as_uint(f);
  return (u & 0x80000000u) ? ~u : (u | 0x80000000u);
}
__device__ __forceinline__ float dec_f(unsigned k) {
  return (k & 0x80000000u) ? __uint_as_float(k & 0x7fffffffu)
                           : __uint_as_float(~k);
}
__device__ __forceinline__ unsigned pack_bf16(float a, float b) {
  bf16x2 h = __float22bfloat162_rn(make_float2(a, b));
  return *(unsigned*)&h;
}
__device__ __forceinline__ float2 unpack_bf16(unsigned u) {
  bf16x2 h = *(bf16x2*)&u;
  return __bfloat1622float2(h);
}
// leaky_relu(v, 0.2) == max(v, 0.2*v)
__device__ __forceinline__ float lrelu(float v) {
  return fmaxf(v, NEG_SLOPE * v);
}
__device__ __forceinline__ float ld_f(const float* p) { return *p; }
__device__ __forceinline__ float ld_f(const bf16* p) {
  return __bfloat162float(*p);
}

// ========================= node GEMM =============================
// out[n][j] = dot(X[n,:K], W[:K,j]), bf16 output. 64 nodes x 128 cols/block,
// 8x4 per thread. SCORES: fused el/er epilogue.
template <int K, typename XT, bool SCORES>
__global__ __launch_bounds__(256) void gemm_tiled(
    const XT* __restrict__ X, const float* __restrict__ W,
    const float* __restrict__ attn_l, const float* __restrict__ attn_r,
    bf16* __restrict__ out, float* __restrict__ el, float* __restrict__ er,
    int N) {
  constexpr int BK = 32;
  constexpr int APAD = 68;
  __shared__ float as[BK * APAD];
  __shared__ float bs[BK * HF];
  const int tid = threadIdx.x;
  const int tx = tid & 31;
  const int ty = tid >> 5;
  const int j4 = tx * 4;
  const int nb = ty * 8;
  const int n0 = blockIdx.x * 64;

  float acc[8][4] = {};
  for (int k0 = 0; k0 < K; k0 += BK) {
#pragma unroll
    for (int i = 0; i < 8; ++i) {
      int idx = i * 256 + tid;
      int kk = idx & 31, nl = idx >> 5;
      int n = n0 + nl, k = k0 + kk;
      float v = 0.f;
      if (n < N && k < K) v = ld_f(&X[(size_t)n * K + k]);
      as[kk * APAD + nl] = v;
    }
#pragma unroll
    for (int i = 0; i < 16; ++i) {
      int idx = i * 256 + tid;
      int kk = idx >> 7, c = idx & 127;
      int k = k0 + kk;
      bs[idx] = (k < K) ? W[(size_t)k * HF + c] : 0.f;
    }
    __syncthreads();
#pragma unroll 8
    for (int kk = 0; kk < BK; ++kk) {
      float4 wv = *(const float4*)&bs[kk * HF + j4];
      float4 a0 = *(const float4*)&as[kk * APAD + nb];
      float4 a1 = *(const float4*)&as[kk * APAD + nb + 4];
      float av[8] = {a0.x, a0.y, a0.z, a0.w, a1.x, a1.y, a1.z, a1.w};
#pragma unroll
      for (int i = 0; i < 8; ++i) {
        acc[i][0] = fmaf(av[i], wv.x, acc[i][0]);
        acc[i][1] = fmaf(av[i], wv.y, acc[i][1]);
        acc[i][2] = fmaf(av[i], wv.z, acc[i][2]);
        acc[i][3] = fmaf(av[i], wv.w, acc[i][3]);
      }
    }
    __syncthreads();
  }
#pragma unroll
  for (int i = 0; i < 8; ++i) {
    int n = n0 + nb + i;
    if (n < N)
      *(uint2*)&out[(size_t)n * HF + j4] =
          make_uint2(pack_bf16(acc[i][0], acc[i][1]),
                     pack_bf16(acc[i][2], acc[i][3]));
  }
  if (SCORES) {
    float al0 = attn_l[j4], al1 = attn_l[j4 + 1];
    float al2 = attn_l[j4 + 2], al3 = attn_l[j4 + 3];
    float ar0 = attn_r[j4], ar1 = attn_r[j4 + 1];
    float ar2 = attn_r[j4 + 2], ar3 = attn_r[j4 + 3];
    const int h = tx >> 3;
#pragma unroll
    for (int i = 0; i < 8; ++i) {
      float pl = acc[i][0] * al0 + acc[i][1] * al1 +
                 acc[i][2] * al2 + acc[i][3] * al3;
      float pr = acc[i][0] * ar0 + acc[i][1] * ar1 +
                 acc[i][2] * ar2 + acc[i][3] * ar3;
      pl += __shfl_xor(pl, 1); pr += __shfl_xor(pr, 1);
      pl += __shfl_xor(pl, 2); pr += __shfl_xor(pr, 2);
      pl += __shfl_xor(pl, 4); pr += __shfl_xor(pr, 4);
      int n = n0 + nb + i;
      if ((tx & 7) == 0 && n < N) {
        el[n * HEADS + h] = pl;
        er[n * HEADS + h] = pr;
      }
    }
  }
}

// ============================ CSR build ====================================
__global__ __launch_bounds__(256) void hist_kernel(
    const int* __restrict__ dst, int* __restrict__ deg, int E) {
  int e = blockIdx.x * 256 + threadIdx.x;
  if (e < E) atomicAdd(&deg[dst[e]], 1);
}

__global__ __launch_bounds__(256) void scan1_kernel(
    const int* __restrict__ deg, int* __restrict__ row_ptr,
    int* __restrict__ bsum, int N) {
  const int base = blockIdx.x * 2048;
  const int tbase = base + threadIdx.x * 8;
  int vals[8];
  int tsum = 0;
#pragma unroll
  for (int i = 0; i < 8; ++i) {
    int idx = tbase + i;
    vals[i] = (idx < N) ? deg[idx] : 0;
    tsum += vals[i];
  }
  const int lane = threadIdx.x & 63, wv = threadIdx.x >> 6;
  int incl = tsum;
#pragma unroll
  for (int off = 1; off < 64; off <<= 1) {
    int nv = __shfl_up(incl, off);
    if (lane >= off) incl += nv;
  }
  __shared__ int wsum[4];
  if (lane == 63) wsum[wv] = incl;
  __syncthreads();
  int woff = 0;
  for (int w = 0; w < wv; ++w) woff += wsum[w];
  int run = woff + incl - tsum;
#pragma unroll
  for (int i = 0; i < 8; ++i) {
    int idx = tbase + i;
    if (idx < N) row_ptr[idx] = run;
    run += vals[i];
  }
  if (threadIdx.x == 255) bsum[blockIdx.x] = woff + incl;
}

__global__ __launch_bounds__(64) void scan2_kernel(
    const int* __restrict__ bsum, int* __restrict__ bpre, int NB) {
  const int lane = threadIdx.x;
  int running = 0;
  for (int c = 0; c < NB; c += 64) {
    int v = (c + lane < NB) ? bsum[c + lane] : 0;
    int incl = v;
#pragma unroll
    for (int off = 1; off < 64; off <<= 1) {
      int nv = __shfl_up(incl, off);
      if (lane >= off) incl += nv;
    }
    if (c + lane < NB) bpre[c + lane] = running + incl - v;
    running += __shfl(incl, 63);
  }
}

__global__ __launch_bounds__(256) void scan3_kernel(
    int* __restrict__ row_ptr, const int* __restrict__ bpre, int N, int E) {
  int t = blockIdx.x * 256 + threadIdx.x;
  if (t < N) row_ptr[t] += bpre[t >> 11];
  if (t == 0) row_ptr[N] = E;
}

__global__ __launch_bounds__(256) void scatter_kernel(
    const int* __restrict__ src, const int* __restrict__ dst,
    const int* __restrict__ row_ptr, int* __restrict__ cursor,
    int* __restrict__ ssorted, int E) {
  int e = blockIdx.x * 256 + threadIdx.x;
  if (e >= E) return;
  int d = dst[e];
  int pos = row_ptr[d] + atomicAdd(&cursor[d], 1);
  ssorted[pos] = src[e];
}

// ============ fused softmax + aggregate (single edge pass) =================
// One wave per node; lane holds cols (2*lane, 2*lane+1), head h = lane>>4.
// 8-edge straight-line unroll (~24 loads in flight), 4-edge + scalar tails.
// alpha = exp(v)/sum(exp), no max-subtraction (v bounded).

#define EDGE_LOAD(i, e_)                                                    \
  int s##i = ssorted[e_];                                                   \
  float x##i; float2 f##i;                                                  \
  {                                                                         \
    float v = el[s##i * HEADS + h] + ern;                                   \
    x##i = __expf(lrelu(v));                                                \
    f##i = unpack_bf16(*(const unsigned*)&feat[(size_t)s##i * HF + c2]);    \
  }
#define EDGE_ACC(i)                                                         \
  ssum += x##i;                                                             \
  ax = fmaf(x##i, f##i.x, ax);                                              \
  ay = fmaf(x##i, f##i.y, ay);

// Layer 1 epilogue: H[n] = elu(inv*agg + res[n] + bias)   (res, H bf16)
__global__ __launch_bounds__(256) void agg1_fused(
    const int* __restrict__ row_ptr, const int* __restrict__ ssorted,
    const float* __restrict__ el, const float* __restrict__ er,
    const bf16* __restrict__ feat, const bf16* __restrict__ res,
    bf16* __restrict__ H, const float* __restrict__ bias, int N) {
  int n = blockIdx.x * 4 + (threadIdx.x >> 6);
  if (n >= N) return;
  const int lane = threadIdx.x & 63;
  const int c2 = lane * 2, h = lane >> 4;
  const int rb = row_ptr[n], re = row_ptr[n + 1];
  const float ern = er[n * HEADS + h];

  float ax = 0.f, ay = 0.f, ssum = 0.f;
  int e = rb;
  for (; e + 7 < re; e += 8) {
    EDGE_LOAD(0, e) EDGE_LOAD(1, e + 1) EDGE_LOAD(2, e + 2)
    EDGE_LOAD(3, e + 3) EDGE_LOAD(4, e + 4) EDGE_LOAD(5, e + 5)
    EDGE_LOAD(6, e + 6) EDGE_LOAD(7, e + 7)
    EDGE_ACC(0) EDGE_ACC(1) EDGE_ACC(2) EDGE_ACC(3)
    EDGE_ACC(4) EDGE_ACC(5) EDGE_ACC(6) EDGE_ACC(7)
  }
  for (; e + 3 < re; e += 4) {
    EDGE_LOAD(0, e) EDGE_LOAD(1, e + 1) EDGE_LOAD(2, e + 2)
    EDGE_LOAD(3, e + 3)
    EDGE_ACC(0) EDGE_ACC(1) EDGE_ACC(2) EDGE_ACC(3)
  }
  for (; e < re; ++e) {
    EDGE_LOAD(0, e)
    EDGE_ACC(0)
  }
  float inv = 1.f / ssum;
  float2 r = unpack_bf16(*(const unsigned*)&res[(size_t)n * HF + c2]);
  float2 bi = *(const float2*)&bias[c2];
  float vx = fmaf(ax, inv, r.x + bi.x);
  float vy = fmaf(ay, inv, r.y + bi.y);
  vx = (vx > 0.f) ? vx : expm1f(vx);
  vy = (vy > 0.f) ? vy : expm1f(vy);
  *(unsigned*)&H[(size_t)n * HF + c2] = pack_bf16(vx, vy);
}

// Layer 2 epilogue: head-mean -> sigmoid gate -> readout atomics.
__global__ __launch_bounds__(256) void agg2_fused(
    const int* __restrict__ row_ptr, const int* __restrict__ ssorted,
    const float* __restrict__ el, const float* __restrict__ er,
    const bf16* __restrict__ feat, const bf16* __restrict__ h1,
    const float* __restrict__ bias, const float* __restrict__ ww,
    const float* __restrict__ wb, const int* __restrict__ gids,
    float* __restrict__ hsum, unsigned* __restrict__ hmax, int N) {
  int n = blockIdx.x * 4 + (threadIdx.x >> 6);
  if (n >= N) return;
  const int lane = threadIdx.x & 63;
  const int c2 = lane * 2, h = lane >> 4;
  const int rb = row_ptr[n], re = row_ptr[n + 1];
  const float ern = er[n * HEADS + h];

  float ax = 0.f, ay = 0.f, ssum = 0.f;
  int e = rb;
  for (; e + 7 < re; e += 8) {
    EDGE_LOAD(0, e) EDGE_LOAD(1, e + 1) EDGE_LOAD(2, e + 2)
    EDGE_LOAD(3, e + 3) EDGE_LOAD(4, e + 4) EDGE_LOAD(5, e + 5)
    EDGE_LOAD(6, e + 6) EDGE_LOAD(7, e + 7)
    EDGE_ACC(0) EDGE_ACC(1) EDGE_ACC(2) EDGE_ACC(3)
    EDGE_ACC(4) EDGE_ACC(5) EDGE_ACC(6) EDGE_ACC(7)
  }
  for (; e + 3 < re; e += 4) {
    EDGE_LOAD(0, e) EDGE_LOAD(1, e + 1) EDGE_LOAD(2, e + 2)
    EDGE_LOAD(3, e + 3)
    EDGE_ACC(0) EDGE_ACC(1) EDGE_ACC(2) EDGE_ACC(3)
  }
  for (; e < re; ++e) {
    EDGE_LOAD(0, e)
    EDGE_ACC(0)
  }
  float inv = 1.f / ssum;
  float2 r = unpack_bf16(*(const unsigned*)&h1[(size_t)n * HF + c2]);
  float2 bi = *(const float2*)&bias[c2];
  ax = fmaf(ax, inv, r.x + bi.x);
  ay = fmaf(ay, inv, r.y + bi.y);
  // head mean: after xor 16,32 every lane holds the sum over its 4-head class
#pragma unroll
  for (int off = 16; off < 64; off <<= 1) {
    ax += __shfl_xor(ax, off);
    ay += __shfl_xor(ay, off);
  }
  ax *= 0.25f;
  ay *= 0.25f;
  // sigmoid gate: dot(node_feats, ww) reduced over the 16-lane col groups
  int c = c2 & 31;
  float d = fmaf(ax, ww[c], ay * ww[c + 1]);
#pragma unroll
  for (int off = 1; off < 16; off <<= 1) d += __shfl_xor(d, off);
  float wv = 1.f / (1.f + __expf(-(d + wb[0])));
  if (lane < 16) {
    int g = gids[n];
    atomicAdd(&hsum[g * OUTF + c], wv * ax);
    atomicAdd(&hsum[g * OUTF + c + 1], wv * ay);
    atomicMax(&hmax[g * OUTF + c], enc_f(ax));
    atomicMax(&hmax[g * OUTF + c + 1], enc_f(ay));
  }
}

// ============================ readout tail =================================
__global__ __launch_bounds__(256) void init_readout_kernel(
    float* __restrict__ hsum, unsigned* __restrict__ hmax, int g32) {
  int t = blockIdx.x * 256 + threadIdx.x;
  if (t >= g32) return;
  hsum[t] = 0.f;
  hmax[t] = NEG_INF_ENC;
}

__global__ __launch_bounds__(256) void final_gemm_kernel(
    const float* __restrict__ hsum, const unsigned* __restrict__ hmax,
    const float* __restrict__ tw, const float* __restrict__ tb,
    float* __restrict__ out, int G) {
  __shared__ float tws[64 * PRED_DIM];
  for (int i = threadIdx.x; i < 64 * PRED_DIM; i += 256) tws[i] = tw[i];
  __syncthreads();
  int g = blockIdx.x * 2 + (threadIdx.x >> 7);
  int p = threadIdx.x & 127;
  if (g >= G) return;
  float acc = tb[p];
#pragma unroll
  for (int k = 0; k < OUTF; ++k)
    acc = fmaf(hsum[g * OUTF + k], tws[k * PRED_DIM + p], acc);
#pragma unroll
  for (int k = 0; k < OUTF; ++k)
    acc = fmaf(dec_f(hmax[g * OUTF + k]), tws[(OUTF + k) * PRED_DIM + p], acc);
  out[(size_t)g * PRED_DIM + p] = acc;
}

static inline int cdiv(long long a, int b) { return (int)((a + b - 1) / b); }

extern "C" void kernel_launch(void* const* d_in, const int* in_sizes, int n_in,
                              void* d_out, int out_size, void* d_ws,
                              size_t ws_size, hipStream_t stream) {
  const float* feats   = (const float*)d_in[0];
  const int*   src     = (const int*)d_in[1];
  const int*   dst     = (const int*)d_in[2];
  const int*   gids    = (const int*)d_in[3];
  const float* fc1_w   = (const float*)d_in[4];
  const float* attn_l1 = (const float*)d_in[5];
  const float* attn_r1 = (const float*)d_in[6];
  const float* res1_w  = (const float*)d_in[7];
  const float* bias1   = (const float*)d_in[8];
  const float* fc2_w   = (const float*)d_in[9];
  const float* attn_l2 = (const float*)d_in[10];
  const float* attn_r2 = (const float*)d_in[11];
  const float* bias2   = (const float*)d_in[12];
  const float* ww      = (const float*)d_in[13];
  const float* wb      = (const float*)d_in[14];
  const float* tw      = (const float*)d_in[15];
  const float* tb      = (const float*)d_in[16];
  float* out = (float*)d_out;

  const int N = in_sizes[0] / IN_FEATS;  // 100000
  const int E = in_sizes[1];             // 900000
  const int G = out_size / PRED_DIM;     // 2048
  const int NB = cdiv(N, 2048);

  // ---- workspace layout ----
  bf16* A = (bf16*)d_ws;                      // N*128 bf16 (feat1/feat2)
  bf16* B = A + (size_t)N * HF;               // N*128 bf16 (res1)
  bf16* H = B + (size_t)N * HF;               // N*128 bf16 (h1)
  float* el = (float*)(H + (size_t)N * HF);   // N*4
  float* er = el + (size_t)N * HEADS;         // N*4
  float* hsum = er + (size_t)N * HEADS;       // G*32
  unsigned* hmax = (unsigned*)(hsum + (size_t)G * OUTF);  // G*32
  int* deg     = (int*)(hmax + (size_t)G * OUTF);  // N
  int* cursor  = deg + N;                          // N
  int* row_ptr = cursor + N;                       // N+1
  int* ssorted = row_ptr + (N + 1);                // E
  int* bsum    = ssorted + E;                      // NB
  int* bpre    = bsum + NB;                        // NB

  const int gblk = cdiv(N, 64);
  const int nwblk = cdiv(N, 4);

  // ===================== CSR build =====================
  hipMemsetAsync(deg, 0, (size_t)N * sizeof(int), stream);
  hipMemsetAsync(cursor, 0, (size_t)N * sizeof(int), stream);
  hist_kernel<<<cdiv(E, 256), 256, 0, stream>>>(dst, deg, E);
  scan1_kernel<<<NB, 256, 0, stream>>>(deg, row_ptr, bsum, N);
  scan2_kernel<<<1, 64, 0, stream>>>(bsum, bpre, NB);
  scan3_kernel<<<cdiv(N, 256), 256, 0, stream>>>(row_ptr, bpre, N, E);
  scatter_kernel<<<cdiv(E, 256), 256, 0, stream>>>(src, dst, row_ptr, cursor,
                                                   ssorted, E);

  // ===================== Layer 1 =====================
  gemm_tiled<IN_FEATS, float, true><<<gblk, 256, 0, stream>>>(
      feats, fc1_w, attn_l1, attn_r1, A, el, er, N);
  gemm_tiled<IN_FEATS, float, false><<<gblk, 256, 0, stream>>>(
      feats, res1_w, nullptr, nullptr, B, nullptr, nullptr, N);
  agg1_fused<<<nwblk, 256, 0, stream>>>(row_ptr, ssorted, el, er, A, B, H,
                                        bias1, N);

  // ===================== Layer 2 =====================
  gemm_tiled<HF, bf16, true><<<gblk, 256, 0, stream>>>(
      H, fc2_w, attn_l2, attn_r2, A, el, er, N);
  init_readout_kernel<<<cdiv(G * OUTF, 256), 256, 0, stream>>>(hsum, hmax,
                                                               G * OUTF);
  agg2_fused<<<nwblk, 256, 0, stream>>>(row_ptr, ssorted, el, er, A, H, bias2,
                                        ww, wb, gids, hsum, hmax, N);

  // ===================== Readout =====================
  final_gemm_kernel<<<cdiv(G, 2), 256, 0, stream>>>(hsum, hmax, tw, tb, out, G);
}